// Round 1
// 170.637 us; speedup vs baseline: 1.1000x; 1.1000x over previous
//
#include <hip/hip_runtime.h>

// Problem constants: B=1024, V=64, DIN=256, DOUT=256, fp32 in/out.
#define EPS 1e-5f

typedef __bf16 bf16_t;
typedef bf16_t bf16x4 __attribute__((ext_vector_type(4)));
typedef bf16_t bf16x8 __attribute__((ext_vector_type(8)));
typedef float  floatx4 __attribute__((ext_vector_type(4)));

// Fragment-pack layouts (verified, rounds 1-3):
//   A-frag chunk (mt, ks, lane): A[m = mt*16 + (lane&15)][k = ks*32 + (lane>>4)*8 + j]
//   B-frag chunk (nt, ks, lane): B[k = ks*32 + (lane>>4)*8 + j][n = nt*16 + (lane&15)]
//   C/D: col = lane&15, row = (lane>>4)*4 + reg

// ---------------------------------------------------------------------------
// K0a: Bp[v][nt16][ks8][lane][8] = bf16(W[v][k][n]); bx==512: adjB = bf16(adj);
//      bx==513: zero g_sum/g_sq (replaces hipMemsetAsync -> one fewer dispatch)
// ---------------------------------------------------------------------------
__global__ __launch_bounds__(256) void k0a_packW(
    const float* __restrict__ W, const float* __restrict__ adj,
    bf16_t* __restrict__ Bp, bf16_t* __restrict__ adjB,
    float* __restrict__ g_sum, float* __restrict__ g_sq) {
  int bx = blockIdx.x, tid = threadIdx.x;
  if (bx == 513) {  // zero the stats accumulators (16384 floats each)
    float4 z = {0.f, 0.f, 0.f, 0.f};
    #pragma unroll
    for (int i = 0; i < 16; ++i) {
      *(float4*)(g_sum + (i * 256 + tid) * 4) = z;
      *(float4*)(g_sq + (i * 256 + tid) * 4) = z;
    }
    return;
  }
  if (bx == 512) {  // adjB[u*64+v] = bf16(adj[u*64+v])
    int base = tid * 16;
    #pragma unroll
    for (int half = 0; half < 2; ++half) {
      float4 f0 = *(const float4*)(adj + base + half * 8);
      float4 f1 = *(const float4*)(adj + base + half * 8 + 4);
      bf16x8 d = {(bf16_t)f0.x, (bf16_t)f0.y, (bf16_t)f0.z, (bf16_t)f0.w,
                  (bf16_t)f1.x, (bf16_t)f1.y, (bf16_t)f1.z, (bf16_t)f1.w};
      *(bf16x8*)(adjB + base + half * 8) = d;
    }
    return;
  }
  int v = bx >> 3, ks = bx & 7, k0 = ks * 32;
  __shared__ __attribute__((aligned(16))) float Ls[32][260];
  const float* Wv = W + (size_t)v * 65536;
  #pragma unroll
  for (int it = 0; it < 8; ++it) {
    int idx = it * 256 + tid;
    int row = idx >> 6, c4 = idx & 63;
    *(float4*)&Ls[row][c4 * 4] = *(const float4*)(Wv + (size_t)(k0 + row) * 256 + c4 * 4);
  }
  __syncthreads();
  #pragma unroll
  for (int it = 0; it < 4; ++it) {
    int cc = it * 256 + tid;
    int nt = cc >> 6, lanec = cc & 63;
    int n = nt * 16 + (lanec & 15), kq = (lanec >> 4) * 8;
    bf16x8 d;
    #pragma unroll
    for (int j = 0; j < 8; ++j) d[j] = (bf16_t)Ls[kq + j][n];
    *(bf16x8*)(Bp + ((size_t)(v * 16 + nt) * 8 + ks) * 512 + lanec * 8) = d;
  }
}

// ---------------------------------------------------------------------------
// K1: h[b,v,o] = feat@W + bias. FUSED A-path (round 4): feat is staged
//     fp32->bf16 into a 64KB XOR-swizzled LDS tile once per block (replaces
//     the old k0b pre-pack kernel: saves a full 96MB HBM pass). k-loop is
//     unchanged: register-prefetched, barrier-free, A-frags now from LDS,
//     B-frags from packed global (Bp). A-LDS is reused as the Cs epilogue
//     staging tile after the k-loop (dead by then).
// ---------------------------------------------------------------------------
__global__ __launch_bounds__(256, 2) void k1_gemm(
    const float* __restrict__ feat, const bf16_t* __restrict__ Bp,
    const float* __restrict__ bias, bf16_t* __restrict__ h,
    float* __restrict__ g_sum, float* __restrict__ g_sq) {
  // 64 KB: A-tile bf16 [128 m][256 k], byte ^= (m&7)<<4 swizzle.
  // Reused after the k-loop as Cs [128][136] bf16 (34.8 KB).
  __shared__ __attribute__((aligned(16))) bf16_t As[128 * 256];
  __shared__ float s_sum[128], s_sq[128];

  int tid = threadIdx.x;
  int lane = tid & 63, wave = tid >> 6;
  int wm = wave >> 1, wn = wave & 1;
  int r16 = lane & 15, quad = lane >> 4;
  int v = blockIdx.x, n0 = blockIdx.y * 128, b0 = blockIdx.z * 128;

  if (tid < 128) { s_sum[tid] = 0.f; s_sq[tid] = 0.f; }

  // ---- stage A: As[m][k] = bf16(feat[b0+m][v][k]), swizzled -------------
  // iter: 64 lanes cover 2 full rows (1KB each) -> perfectly coalesced.
  const float* fv = feat + (size_t)b0 * 16384 + v * 256;
  #pragma unroll
  for (int it = 0; it < 16; ++it) {
    int idx = it * 256 + tid;           // 0..4095 (128 rows x 32 chunks)
    int m = idx >> 5, k0 = (idx & 31) * 8;
    float4 f0 = *(const float4*)(fv + (size_t)m * 16384 + k0);
    float4 f1 = *(const float4*)(fv + (size_t)m * 16384 + k0 + 4);
    bf16x8 d = {(bf16_t)f0.x, (bf16_t)f0.y, (bf16_t)f0.z, (bf16_t)f0.w,
                (bf16_t)f1.x, (bf16_t)f1.y, (bf16_t)f1.z, (bf16_t)f1.w};
    int byte = (m * 512 + k0 * 2) ^ ((m & 7) << 4);
    *(bf16x8*)((char*)As + byte) = d;
  }
  __syncthreads();

  // ---- k-loop: A from swizzled LDS, B from packed global ----------------
  floatx4 acc[4][4] = {};

  const bf16_t* bpb[4];
  #pragma unroll
  for (int ni = 0; ni < 4; ++ni) {
    int nt = blockIdx.y * 8 + wn * 4 + ni;
    bpb[ni] = Bp + ((size_t)(v * 16 + nt) * 8) * 512 + lane * 8;
  }

  auto lda = [&](int mi, int ks) -> bf16x8 {
    int m = wm * 64 + mi * 16 + r16;
    int byte = (m * 512 + ks * 64 + quad * 16) ^ ((m & 7) << 4);
    return *(const bf16x8*)((const char*)As + byte);
  };

  bf16x8 ac[4], bc[4], an[4], bn[4];
  #pragma unroll
  for (int mi = 0; mi < 4; ++mi) ac[mi] = lda(mi, 0);
  #pragma unroll
  for (int ni = 0; ni < 4; ++ni) bc[ni] = *(const bf16x8*)bpb[ni];

  #pragma unroll
  for (int ks = 0; ks < 8; ++ks) {
    if (ks < 7) {
      #pragma unroll
      for (int mi = 0; mi < 4; ++mi) an[mi] = lda(mi, ks + 1);
      #pragma unroll
      for (int ni = 0; ni < 4; ++ni) bn[ni] = *(const bf16x8*)(bpb[ni] + (ks + 1) * 512);
    }
    #pragma unroll
    for (int mi = 0; mi < 4; ++mi)
      #pragma unroll
      for (int ni = 0; ni < 4; ++ni)
        acc[mi][ni] = __builtin_amdgcn_mfma_f32_16x16x32_bf16(
            ac[mi], bc[ni], acc[mi][ni], 0, 0, 0);
    if (ks < 7) {
      #pragma unroll
      for (int mi = 0; mi < 4; ++mi) ac[mi] = an[mi];
      #pragma unroll
      for (int ni = 0; ni < 4; ++ni) bc[ni] = bn[ni];
    }
  }

  __syncthreads();  // all A-LDS reads done; safe to reuse as Cs

  bf16_t* Cs = As;  // [128][136] bf16 = 34.8 KB <= 64 KB

  float bias_r[4];
  #pragma unroll
  for (int ni = 0; ni < 4; ++ni)
    bias_r[ni] = bias[v * 256 + n0 + wn * 64 + ni * 16 + r16];

  #pragma unroll
  for (int ni = 0; ni < 4; ++ni) {
    int ncol = wn * 64 + ni * 16 + r16;
    float psum = 0.f, psq = 0.f;
    #pragma unroll
    for (int mi = 0; mi < 4; ++mi) {
      #pragma unroll
      for (int r = 0; r < 4; ++r) {
        int mrow = wm * 64 + mi * 16 + quad * 4 + r;
        float val = acc[mi][ni][r] + bias_r[ni];
        bf16_t hbv = (bf16_t)val;
        Cs[mrow * 136 + ncol] = hbv;
        float hf = (float)hbv;  // stats from STORED value (self-consistent BN)
        psum += hf; psq += hf * hf;
      }
    }
    atomicAdd(&s_sum[ncol], psum);
    atomicAdd(&s_sq[ncol], psq);
  }
  __syncthreads();

  bf16_t* hp = h + (size_t)v * 256 + n0;
  int col0 = (tid & 15) * 8;
  #pragma unroll
  for (int it = 0; it < 8; ++it) {
    int row = it * 16 + (tid >> 4);
    *(bf16x8*)(hp + (size_t)(b0 + row) * 16384 + col0) = *(const bf16x8*)&Cs[row * 136 + col0];
  }
  if (tid < 128) {
    atomicAdd(&g_sum[v * 256 + n0 + tid], s_sum[tid]);
    atomicAdd(&g_sq[v * 256 + n0 + tid], s_sq[tid]);
  }
}

// ---------------------------------------------------------------------------
// K2: fold BN into per-(v,o) affine, emitted as BF16 (halves k4 param traffic)
// ---------------------------------------------------------------------------
__global__ __launch_bounds__(256) void k2_stats(
    const float* __restrict__ g_sum, const float* __restrict__ g_sq,
    const float* __restrict__ gamma, const float* __restrict__ beta,
    bf16_t* __restrict__ a_bf, bf16_t* __restrict__ c_bf) {
  int idx = blockIdx.x * 256 + threadIdx.x;
  float s = g_sum[idx], q = g_sq[idx];
  float mean = s * (1.0f / 1024.0f);
  float var = fmaxf(q * (1.0f / 1024.0f) - mean * mean, 0.f);
  float rs = rsqrtf(var + EPS);
  float a = gamma[idx] * rs;
  a_bf[idx] = (bf16_t)a;
  c_bf[idx] = (bf16_t)(beta[idx] - mean * a);
}

// ---------------------------------------------------------------------------
// K4: out[b,u,o] = relu(sum_v adj[u,v] * (a*h+c)[b,v,o]) via bf16 MFMA.
//     One block per b. Stage hbn transposed in LDS (v-rotation swizzle), mix
//     with MFMA (A=adjB L1-hot), then re-stage out through LDS (reusing hsT)
//     for FULL-LINE dwordx4 stores.
// ---------------------------------------------------------------------------
__global__ __launch_bounds__(256) void k4_mix(
    const bf16_t* __restrict__ h, const bf16_t* __restrict__ adjB,
    const bf16_t* __restrict__ a_bf, const bf16_t* __restrict__ c_bf,
    float* __restrict__ out) {
  __shared__ unsigned int hsT[256 * 33];  // 33792B; reused as f32 [32][260] later
  int tid = threadIdx.x;
  int lane = tid & 63, w = tid >> 6;
  int r16 = lane & 15, quad = lane >> 4;
  int b = blockIdx.x;
  const bf16_t* hb = h + (size_t)b * 16384;

  // A-fragments (adjB 8KB, L1-hot): frag (mi, ks): u=mi*16+r16, k=ks*32+quad*8
  bf16x8 afr[4][2];
  #pragma unroll
  for (int mi = 0; mi < 4; ++mi)
    #pragma unroll
    for (int ks = 0; ks < 2; ++ks)
      afr[mi][ks] = *(const bf16x8*)(adjB + (mi * 16 + r16) * 64 + ks * 32 + quad * 8);

  // stage hbn^T: hsT[o][v'] with v rotated by (o&56) (breaks 8-way wr conflicts)
  #pragma unroll
  for (int i = 0; i < 4; ++i) {
    int idx2 = i * 256 + tid;
    int o8 = (idx2 & 31) * 8;
    int v0 = (idx2 >> 5) * 2;
    bf16x8 h0 = *(const bf16x8*)(hb + (size_t)v0 * 256 + o8);
    bf16x8 h1 = *(const bf16x8*)(hb + (size_t)(v0 + 1) * 256 + o8);
    bf16x8 a0 = *(const bf16x8*)(a_bf + v0 * 256 + o8);
    bf16x8 a1 = *(const bf16x8*)(a_bf + (v0 + 1) * 256 + o8);
    bf16x8 c0 = *(const bf16x8*)(c_bf + v0 * 256 + o8);
    bf16x8 c1 = *(const bf16x8*)(c_bf + (v0 + 1) * 256 + o8);
    #pragma unroll
    for (int j = 0; j < 8; ++j) {
      int o = o8 + j;
      unsigned short lo, hi;
      bf16_t d0 = (bf16_t)fmaf((float)h0[j], (float)a0[j], (float)c0[j]);
      bf16_t d1 = (bf16_t)fmaf((float)h1[j], (float)a1[j], (float)c1[j]);
      __builtin_memcpy(&lo, &d0, 2);
      __builtin_memcpy(&hi, &d1, 2);
      int vr = (v0 + (o & 56)) & 63;
      hsT[o * 33 + (vr >> 1)] = (unsigned int)lo | ((unsigned int)hi << 16);
    }
  }
  __syncthreads();

  // mix: wave w -> o-range w*64..+64 (nt=w*4+ni), all 4 u-tiles, 2 ksteps
  floatx4 acc[4][4] = {};
  #pragma unroll
  for (int ks = 0; ks < 2; ++ks) {
    bf16x8 bfr[4];
    #pragma unroll
    for (int ni = 0; ni < 4; ++ni) {
      int o = (w * 4 + ni) * 16 + r16;
      int vbase = ks * 32 + quad * 8;
      int vr = (vbase + (o & 56)) & 63;
      const unsigned int* src = &hsT[o * 33 + (vr >> 1)];
      unsigned int tmp[4] = {src[0], src[1], src[2], src[3]};
      __builtin_memcpy(&bfr[ni], tmp, 16);
    }
    #pragma unroll
    for (int mi = 0; mi < 4; ++mi)
      #pragma unroll
      for (int ni = 0; ni < 4; ++ni)
        acc[mi][ni] = __builtin_amdgcn_mfma_f32_16x16x32_bf16(
            afr[mi][ks], bfr[ni], acc[mi][ni], 0, 0, 0);
  }

  // epilogue: relu into LDS f32 tile (u-halves), then full-line dwordx4 stores
  float* Lf = (float*)hsT;  // [32][260] = 33280B fits in hsT
  float* ob = out + (size_t)b * 16384;
  #pragma unroll
  for (int half = 0; half < 2; ++half) {
    __syncthreads();  // previous use of hsT/Lf complete
    #pragma unroll
    for (int mi2 = 0; mi2 < 2; ++mi2) {
      int mi = half * 2 + mi2;
      #pragma unroll
      for (int ni = 0; ni < 4; ++ni) {
        int o = (w * 4 + ni) * 16 + r16;
        #pragma unroll
        for (int r = 0; r < 4; ++r) {
          int ul = mi2 * 16 + quad * 4 + r;  // u-local 0..31
          Lf[ul * 260 + o] = fmaxf(acc[mi][ni][r], 0.f);
        }
      }
    }
    __syncthreads();
    // 32 rows x 256 o fp32 -> one full 1KB row per wave-instr
    #pragma unroll
    for (int it = 0; it < 8; ++it) {
      int cid = it * 256 + tid;
      int row = cid >> 6, c4 = cid & 63;
      float4 val = *(const float4*)&Lf[row * 260 + c4 * 4];
      *(float4*)(ob + (size_t)(half * 32 + row) * 256 + c4 * 4) = val;
    }
  }
}

// ---------------------------------------------------------------------------
extern "C" void kernel_launch(void* const* d_in, const int* in_sizes, int n_in,
                              void* d_out, int out_size, void* d_ws, size_t ws_size,
                              hipStream_t stream) {
  const float* feat  = (const float*)d_in[0];  // [1024, 64, 256]
  const float* adj   = (const float*)d_in[1];  // [64, 64]
  const float* W     = (const float*)d_in[2];  // [64, 256, 256]
  const float* bias  = (const float*)d_in[3];  // [64, 256]
  const float* gamma = (const float*)d_in[4];  // [64, 256]
  const float* beta  = (const float*)d_in[5];  // [64, 256]
  float* out = (float*)d_out;                  // [1024, 64, 256]

  char* ws = (char*)d_ws;                      // needs ~41.3 MB
  bf16_t* Bp   = (bf16_t*)ws;                               // 8.4 MB packed W
  bf16_t* hbuf = (bf16_t*)(ws + (size_t)(9u << 20));        // 32 MB [B][V][O] bf16
  char* tail   = ws + (size_t)(41u << 20);
  float* g_sum = (float*)tail;                              // 64 KB
  float* g_sq  = (float*)(tail + 65536);                    // 64 KB
  bf16_t* a_bf = (bf16_t*)(tail + 2 * 65536);               // 32 KB
  bf16_t* c_bf = (bf16_t*)(tail + 2 * 65536 + 32768);       // 32 KB
  bf16_t* adjB = (bf16_t*)(tail + 3 * 65536);               //  8 KB

  k0a_packW<<<514, 256, 0, stream>>>(W, adj, Bp, adjB, g_sum, g_sq);
  k1_gemm<<<dim3(64, 2, 8), 256, 0, stream>>>(feat, Bp, bias, hbuf, g_sum, g_sq);
  k2_stats<<<64, 256, 0, stream>>>(g_sum, g_sq, gamma, beta, a_bf, c_bf);
  k4_mix<<<1024, 256, 0, stream>>>(hbuf, adjB, a_bf, c_bf, out);
}